// Round 1
// baseline (2467.653 us; speedup 1.0000x reference)
//
#include <hip/hip_runtime.h>
#include <math.h>

#define HCX 128   // H*C
#define CCX 32    // per-head channels
#define EDX 64    // edge feature dim

// ---------------- CSR build ----------------
__global__ __launch_bounds__(256) void k_zero_deg(int* __restrict__ deg, int n) {
    int t = blockIdx.x * 256 + threadIdx.x;
    if (t < n) deg[t] = 0;
}

__global__ __launch_bounds__(256) void k_hist(const int* __restrict__ dst, int* __restrict__ deg, int nE) {
    int t = blockIdx.x * 256 + threadIdx.x;
    if (t < nE) atomicAdd(&deg[dst[t]], 1);
}

__global__ __launch_bounds__(1024) void k_scan(const int* __restrict__ deg, int* __restrict__ csr_off,
                                               int* __restrict__ cursor, int nN) {
    __shared__ int sums[1024];
    int t = threadIdx.x;
    int chunk = (nN + 1023) >> 10;
    int lo = min(t * chunk, nN), hi = min(lo + chunk, nN);
    int s = 0;
    for (int i = lo; i < hi; ++i) s += deg[i];
    sums[t] = s;
    __syncthreads();
    for (int off = 1; off < 1024; off <<= 1) {
        int v = (t >= off) ? sums[t - off] : 0;
        __syncthreads();
        sums[t] += v;
        __syncthreads();
    }
    int run = (t == 0) ? 0 : sums[t - 1];
    for (int i = lo; i < hi; ++i) {
        csr_off[i] = run; cursor[i] = run;
        run += deg[i];
    }
    if (t == 1023) csr_off[nN] = sums[1023];
}

__global__ __launch_bounds__(256) void k_scatter(const int* __restrict__ dst, int* __restrict__ cursor,
                                                 int* __restrict__ edge_sorted, int nE) {
    int t = blockIdx.x * 256 + threadIdx.x;
    if (t < nE) {
        int pos = atomicAdd(&cursor[dst[t]], 1);
        edge_sorted[pos] = t;
    }
}

// ---------------- node linear: [q|k|v|s] = concat(h,x) @ {Wq,Wk,Wv,Ws} + bias ----------------
// grid.x = ceil(nN/64), grid.y = 8 (4 mats x 2 col-halves), block = 256
__global__ __launch_bounds__(256) void k_node_linear(
    const float* __restrict__ pH, int w0,
    const float* __restrict__ pX, int w1,
    const float* __restrict__ Wq, const float* __restrict__ bq,
    const float* __restrict__ Wk, const float* __restrict__ bk,
    const float* __restrict__ Wv, const float* __restrict__ bv,
    const float* __restrict__ Ws, const float* __restrict__ bs,
    float* __restrict__ qkvs, int nN)
{
    const int din = w0 + w1;
    const int g  = blockIdx.y >> 1;
    const int jb = (blockIdx.y & 1) * 64;
    const float* W = (g == 0) ? Wq : (g == 1) ? Wk : (g == 2) ? Wv : Ws;
    const float* B = (g == 0) ? bq : (g == 1) ? bk : (g == 2) ? bv : bs;
    const int row0 = blockIdx.x * 64;

    __shared__ float As[16][68];   // [k][m], padded to dodge write conflicts
    __shared__ float Bs[16][64];   // [k][j]

    const int tid = threadIdx.x;
    const int tx = tid & 15, ty = tid >> 4;
    const int ak = tid & 15, am = tid >> 4;
    const int bj = tid & 63, bk_ = tid >> 6;

    float acc[4][4] = {{0.f}};

    for (int k0 = 0; k0 < din; k0 += 16) {
        #pragma unroll
        for (int i = 0; i < 4; ++i) {
            int m   = am + i * 16;
            int row = row0 + m;
            int kc  = k0 + ak;
            float v = 0.f;
            if (row < nN)
                v = (kc < w0) ? pH[(size_t)row * w0 + kc] : pX[(size_t)row * w1 + (kc - w0)];
            As[ak][m] = v;
        }
        #pragma unroll
        for (int i = 0; i < 4; ++i) {
            int kr = bk_ + i * 4;
            Bs[kr][bj] = W[(size_t)(k0 + kr) * HCX + jb + bj];
        }
        __syncthreads();
        #pragma unroll
        for (int kk = 0; kk < 16; ++kk) {
            float a0 = As[kk][ty * 4 + 0], a1 = As[kk][ty * 4 + 1];
            float a2 = As[kk][ty * 4 + 2], a3 = As[kk][ty * 4 + 3];
            float4 b = *(const float4*)&Bs[kk][tx * 4];
            acc[0][0] += a0 * b.x; acc[0][1] += a0 * b.y; acc[0][2] += a0 * b.z; acc[0][3] += a0 * b.w;
            acc[1][0] += a1 * b.x; acc[1][1] += a1 * b.y; acc[1][2] += a1 * b.z; acc[1][3] += a1 * b.w;
            acc[2][0] += a2 * b.x; acc[2][1] += a2 * b.y; acc[2][2] += a2 * b.z; acc[2][3] += a2 * b.w;
            acc[3][0] += a3 * b.x; acc[3][1] += a3 * b.y; acc[3][2] += a3 * b.z; acc[3][3] += a3 * b.w;
        }
        __syncthreads();
    }

    float b0 = B[jb + tx * 4 + 0], b1 = B[jb + tx * 4 + 1];
    float b2 = B[jb + tx * 4 + 2], b3 = B[jb + tx * 4 + 3];
    float* outp = qkvs + (size_t)g * nN * HCX;
    #pragma unroll
    for (int i = 0; i < 4; ++i) {
        int row = row0 + ty * 4 + i;
        if (row < nN) {
            float* o = outp + (size_t)row * HCX + jb + tx * 4;
            o[0] = acc[i][0] + b0; o[1] = acc[i][1] + b1;
            o[2] = acc[i][2] + b2; o[3] = acc[i][3] + b3;
        }
    }
}

// ---------------- qWe[n,h,d] = sum_c q[n,h,c] * We[d, h*32+c] ----------------
// grid = nN, block = 256 (h = tid/64, d = tid%64)
__global__ __launch_bounds__(256) void k_qwe(const float* __restrict__ qplane,
                                             const float* __restrict__ We,
                                             float* __restrict__ qWe, int nN)
{
    int n = blockIdx.x;
    int h = threadIdx.x >> 6;
    int d = threadIdx.x & 63;
    const float* q = qplane + (size_t)n * HCX + h * CCX;
    const float* w = We + (size_t)d * HCX + h * CCX;
    float s = 0.f;
    #pragma unroll
    for (int c = 0; c < CCX; c += 4) {
        float4 qv = *(const float4*)(q + c);
        float4 wv = *(const float4*)(w + c);
        s += qv.x * wv.x + qv.y * wv.y + qv.z * wv.z + qv.w * wv.w;
    }
    qWe[(size_t)n * 256 + h * 64 + d] = s;
}

// ---------------- alpha[e,h] = (q[dst]·k[src] + ea[e]·qWe[dst]) / sqrt(C) ----------------
// thread t: e = t/4, h = t%4
__global__ __launch_bounds__(256) void k_alpha(
    const float* __restrict__ qkvs, const float* __restrict__ qWe,
    const float* __restrict__ ea, const int* __restrict__ src, const int* __restrict__ dst,
    float* __restrict__ alpha, int nN, int nE)
{
    int t = blockIdx.x * 256 + threadIdx.x;
    int e = t >> 2, h = t & 3;
    if (e >= nE) return;
    int sn = src[e], dn = dst[e];
    const float* q = qkvs + (size_t)dn * HCX + h * CCX;
    const float* k = qkvs + (size_t)nN * HCX + (size_t)sn * HCX + h * CCX;
    float s = 0.f;
    #pragma unroll
    for (int c = 0; c < CCX; c += 4) {
        float4 qv = *(const float4*)(q + c);
        float4 kv = *(const float4*)(k + c);
        s += qv.x * kv.x + qv.y * kv.y + qv.z * kv.z + qv.w * kv.w;
    }
    const float* qw = qWe + (size_t)dn * 256 + h * 64;
    const float* ev = ea + (size_t)e * EDX;
    #pragma unroll
    for (int d = 0; d < EDX; d += 4) {
        float4 av = *(const float4*)(ev + d);
        float4 wv = *(const float4*)(qw + d);
        s += av.x * wv.x + av.y * wv.y + av.z * wv.z + av.w * wv.w;
    }
    alpha[t] = s * 0.17677669529663687f;  // 1/sqrt(32)
}

// ---------------- per-dst-node softmax + aggregation ----------------
// block = 256 (4 waves), wave w handles node blockIdx*4+w; lane owns channels l and 64+l
__global__ __launch_bounds__(256) void k_aggregate(
    const float* __restrict__ qkvs, const float* __restrict__ alpha,
    const float* __restrict__ ea,   const float* __restrict__ We,
    const int* __restrict__ src,
    const int* __restrict__ csr_off, const int* __restrict__ edge_sorted,
    float* __restrict__ hout, int nN)
{
    __shared__ float wea_s[4][256];  // [wave][h*64+d]
    int wv = threadIdx.x >> 6, l = threadIdx.x & 63;
    int n = blockIdx.x * 4 + wv;
    bool active = n < nN;
    int o0 = 0, o1 = 0;
    if (active) { o0 = csr_off[n]; o1 = csr_off[n + 1]; }
    int deg = o1 - o0;
    const float* vpl = qkvs + 2 * (size_t)nN * HCX;

    // ---- max over incoming edges, per head ----
    float mx0 = -INFINITY, mx1 = -INFINITY, mx2 = -INFINITY, mx3 = -INFINITY;
    for (int i = l; i < deg; i += 64) {
        int eid = edge_sorted[o0 + i];
        const float* al = alpha + (size_t)eid * 4;
        mx0 = fmaxf(mx0, al[0]); mx1 = fmaxf(mx1, al[1]);
        mx2 = fmaxf(mx2, al[2]); mx3 = fmaxf(mx3, al[3]);
    }
    #pragma unroll
    for (int s = 32; s > 0; s >>= 1) {
        mx0 = fmaxf(mx0, __shfl_xor(mx0, s));
        mx1 = fmaxf(mx1, __shfl_xor(mx1, s));
        mx2 = fmaxf(mx2, __shfl_xor(mx2, s));
        mx3 = fmaxf(mx3, __shfl_xor(mx3, s));
    }

    // ---- accumulate exp-weighted v and edge_attr ----
    float den0 = 0.f, den1 = 0.f, den2 = 0.f, den3 = 0.f;
    float m0 = 0.f, m1 = 0.f;
    float w0 = 0.f, w1 = 0.f, w2 = 0.f, w3 = 0.f;
    int hsel = l >> 5;  // head of channel l within its half
    for (int i = 0; i < deg; ++i) {
        int eid = edge_sorted[o0 + i];
        int sn  = src[eid];
        const float* al = alpha + (size_t)eid * 4;
        float e0 = __expf(al[0] - mx0), e1 = __expf(al[1] - mx1);
        float e2 = __expf(al[2] - mx2), e3 = __expf(al[3] - mx3);
        den0 += e0; den1 += e1; den2 += e2; den3 += e3;
        float ex1 = hsel ? e1 : e0;
        float ex2 = hsel ? e3 : e2;
        const float* vr = vpl + (size_t)sn * HCX;
        m0 += ex1 * vr[l];
        m1 += ex2 * vr[64 + l];
        float eav = ea[(size_t)eid * EDX + l];
        w0 += e0 * eav; w1 += e1 * eav; w2 += e2 * eav; w3 += e3 * eav;
    }
    wea_s[wv][0 * 64 + l] = w0; wea_s[wv][1 * 64 + l] = w1;
    wea_s[wv][2 * 64 + l] = w2; wea_s[wv][3 * 64 + l] = w3;
    __syncthreads();

    // ---- epilogue: out = (m + wea@We)/den + skip ----
    float acc1 = m0, acc2 = m1;
    int h1 = hsel, h2 = 2 + hsel;
    #pragma unroll 8
    for (int d = 0; d < 64; ++d) {
        acc1 += wea_s[wv][h1 * 64 + d] * We[(size_t)d * HCX + l];
        acc2 += wea_s[wv][h2 * 64 + d] * We[(size_t)d * HCX + 64 + l];
    }
    if (active) {
        float d1 = (hsel ? den1 : den0) + 1e-16f;
        float d2 = (hsel ? den3 : den2) + 1e-16f;
        const float* spl = qkvs + 3 * (size_t)nN * HCX + (size_t)n * HCX;
        hout[(size_t)n * HCX + l]      = acc1 / d1 + spl[l];
        hout[(size_t)n * HCX + 64 + l] = acc2 / d2 + spl[64 + l];
    }
}

// ---------------- final: out = h @ Wout + bout ----------------
__global__ __launch_bounds__(256) void k_out(const float* __restrict__ h,
                                             const float* __restrict__ Wout,
                                             const float* __restrict__ bout,
                                             float* __restrict__ out, int nN)
{
    __shared__ float hs[8][128];
    int nb = blockIdx.x * 8;
    for (int i = threadIdx.x; i < 8 * 128; i += 256) {
        int r = i >> 7, c = i & 127;
        int row = nb + r;
        hs[r][c] = (row < nN) ? h[(size_t)row * 128 + c] : 0.f;
    }
    __syncthreads();
    int r = threadIdx.x >> 5, col = threadIdx.x & 31;
    int row = nb + r;
    if (row < nN) {
        float s = bout[col];
        #pragma unroll 16
        for (int c = 0; c < 128; ++c) s += hs[r][c] * Wout[c * 32 + col];
        out[(size_t)row * 32 + col] = s;
    }
}

// ---------------- host ----------------
static inline size_t align_up(size_t v, size_t a) { return (v + a - 1) & ~(a - 1); }

extern "C" void kernel_launch(void* const* d_in, const int* in_sizes, int n_in,
                              void* d_out, int out_size, void* d_ws, size_t ws_size,
                              hipStream_t stream)
{
    const float* x  = (const float*)d_in[0];
    const int*   ei = (const int*)d_in[1];
    const float* ea = (const float*)d_in[2];
    const int nN = in_sizes[0] / 256;
    const int nE = in_sizes[1] / 2;
    const int* src = ei;
    const int* dst = ei + nE;

    // workspace layout
    char* p = (char*)d_ws;
    size_t off = 0;
    auto take = [&](size_t bytes) { void* r = p + off; off = align_up(off + bytes, 256); return r; };
    int* csr_off     = (int*)take((size_t)(nN + 1) * 4);
    int* cursor      = (int*)take((size_t)nN * 4);
    int* deg         = (int*)take((size_t)nN * 4);
    int* edge_sorted = (int*)take((size_t)nE * 4);
    float* qkvs  = (float*)take((size_t)4 * nN * HCX * 4);
    float* qWe   = (float*)take((size_t)nN * 256 * 4);
    float* alpha = (float*)take((size_t)nE * 4 * 4);
    float* h0    = (float*)take((size_t)nN * HCX * 4);
    float* h1    = (float*)take((size_t)nN * HCX * 4);
    (void)ws_size; (void)n_in; (void)out_size;

    // CSR by dst (fixed across layers)
    k_zero_deg<<<(nN + 255) / 256, 256, 0, stream>>>(deg, nN);
    k_hist<<<(nE + 255) / 256, 256, 0, stream>>>(dst, deg, nE);
    k_scan<<<1, 1024, 0, stream>>>(deg, csr_off, cursor, nN);
    k_scatter<<<(nE + 255) / 256, 256, 0, stream>>>(dst, cursor, edge_sorted, nE);

    auto layer = [&](const float* pH, int w0, int base, float* hout) {
        const float* Wq = (const float*)d_in[base + 0];
        const float* bq = (const float*)d_in[base + 1];
        const float* Wk = (const float*)d_in[base + 2];
        const float* bk = (const float*)d_in[base + 3];
        const float* Wv = (const float*)d_in[base + 4];
        const float* bv = (const float*)d_in[base + 5];
        const float* We = (const float*)d_in[base + 6];
        const float* Ws = (const float*)d_in[base + 7];
        const float* bs = (const float*)d_in[base + 8];
        dim3 grid((nN + 63) / 64, 8);
        k_node_linear<<<grid, 256, 0, stream>>>(pH, w0, x, 256,
                                                Wq, bq, Wk, bk, Wv, bv, Ws, bs, qkvs, nN);
        k_qwe<<<nN, 256, 0, stream>>>(qkvs, We, qWe, nN);
        k_alpha<<<(nE * 4 + 255) / 256, 256, 0, stream>>>(qkvs, qWe, ea, src, dst, alpha, nN, nE);
        k_aggregate<<<(nN + 3) / 4, 256, 0, stream>>>(qkvs, alpha, ea, We, src,
                                                      csr_off, edge_sorted, hout, nN);
    };

    layer(nullptr, 0,   3,  h0);   // layer 0: input = x (din 256)
    layer(h0, HCX,  12, h1);       // layer 1: input = [h0 | x] (din 384)
    layer(h1, HCX,  21, h0);       // layer 2: input = [h1 | x] (din 384)

    k_out<<<(nN + 7) / 8, 256, 0, stream>>>(h0, (const float*)d_in[30], (const float*)d_in[31],
                                            (float*)d_out, nN);
}

// Round 4
// 1130.261 us; speedup vs baseline: 2.1833x; 2.1833x over previous
//
#include <hip/hip_runtime.h>
#include <hip/hip_bf16.h>
#include <math.h>

#define HCX 128   // H*C
#define EDX 64    // edge feature dim
#define KPAD 384  // unified GEMM K (layer 0 zero-pads first 128)

typedef short bf16x8 __attribute__((ext_vector_type(8)));
typedef float f32x4  __attribute__((ext_vector_type(4)));

__device__ __forceinline__ short f2bf(float v) {
    __hip_bfloat16 b = __float2bfloat16(v);
    return *reinterpret_cast<short*>(&b);
}
__device__ __forceinline__ float bf2f(short s) {
    __hip_bfloat16 b = *reinterpret_cast<__hip_bfloat16*>(&s);
    return __bfloat162float(b);
}
__device__ __forceinline__ void gload16(const short* g, short* l) {
    __builtin_amdgcn_global_load_lds((const __attribute__((address_space(1))) void*)g,
                                     (__attribute__((address_space(3))) void*)l, 16, 0, 0);
}

// ---------------- CSR build ----------------
__global__ __launch_bounds__(256) void k_zero_deg(int* __restrict__ deg, int n) {
    int t = blockIdx.x * 256 + threadIdx.x;
    if (t < n) deg[t] = 0;
}

__global__ __launch_bounds__(256) void k_hist(const int* __restrict__ dst, int* __restrict__ deg, int nE) {
    int t = blockIdx.x * 256 + threadIdx.x;
    if (t < nE) atomicAdd(&deg[dst[t]], 1);
}

__global__ __launch_bounds__(1024) void k_scan(const int* __restrict__ deg, int* __restrict__ csr_off,
                                               int* __restrict__ cursor, int nN) {
    __shared__ int sums[1024];
    int t = threadIdx.x;
    int chunk = (nN + 1023) >> 10;
    int lo = min(t * chunk, nN), hi = min(lo + chunk, nN);
    int s = 0;
    for (int i = lo; i < hi; ++i) s += deg[i];
    sums[t] = s;
    __syncthreads();
    for (int off = 1; off < 1024; off <<= 1) {
        int v = (t >= off) ? sums[t - off] : 0;
        __syncthreads();
        sums[t] += v;
        __syncthreads();
    }
    int run = (t == 0) ? 0 : sums[t - 1];
    for (int i = lo; i < hi; ++i) {
        csr_off[i] = run; cursor[i] = run;
        run += deg[i];
    }
    if (t == 1023) csr_off[nN] = sums[1023];
}

__global__ __launch_bounds__(256) void k_scatter(const int* __restrict__ dst, const int* __restrict__ src,
                                                 int* __restrict__ cursor,
                                                 int* __restrict__ edge_sorted, int* __restrict__ src_sorted,
                                                 int nE) {
    int t = blockIdx.x * 256 + threadIdx.x;
    if (t < nE) {
        int pos = atomicAdd(&cursor[dst[t]], 1);
        edge_sorted[pos] = t;
        src_sorted[pos]  = src[t];
    }
}

// ---------------- bf16 hi/lo conversions ----------------
// A layout: [Mpad][384] bf16 (hi & lo planes); cols 0..127 = h-part, 128..383 = x-part.
__global__ __launch_bounds__(256) void k_cvt_h(const float* __restrict__ pH, int has_h,
                                               short* __restrict__ Ah, short* __restrict__ Al,
                                               int nN, int Mpad)
{
    int t = blockIdx.x * 256 + threadIdx.x;           // (row, col-quad)
    int row = t >> 5;
    if (row >= Mpad) return;
    int c0 = (t & 31) * 4;
    float4 v = make_float4(0.f, 0.f, 0.f, 0.f);
    if (has_h && row < nN) v = *(const float4*)(pH + (size_t)row * HCX + c0);
    short4 hs, ls;
    hs.x = f2bf(v.x); ls.x = f2bf(v.x - bf2f(hs.x));
    hs.y = f2bf(v.y); ls.y = f2bf(v.y - bf2f(hs.y));
    hs.z = f2bf(v.z); ls.z = f2bf(v.z - bf2f(hs.z));
    hs.w = f2bf(v.w); ls.w = f2bf(v.w - bf2f(hs.w));
    *(short4*)(Ah + (size_t)row * KPAD + c0) = hs;
    *(short4*)(Al + (size_t)row * KPAD + c0) = ls;
}

__global__ __launch_bounds__(256) void k_cvt_x(const float* __restrict__ x,
                                               short* __restrict__ Ah, short* __restrict__ Al,
                                               int nN, int Mpad)
{
    int t = blockIdx.x * 256 + threadIdx.x;           // (row, col-quad) over 256 x-cols
    int row = t >> 6;
    if (row >= Mpad) return;
    int c0 = (t & 63) * 4;
    float4 v = make_float4(0.f, 0.f, 0.f, 0.f);
    if (row < nN) v = *(const float4*)(x + (size_t)row * 256 + c0);
    short4 hs, ls;
    hs.x = f2bf(v.x); ls.x = f2bf(v.x - bf2f(hs.x));
    hs.y = f2bf(v.y); ls.y = f2bf(v.y - bf2f(hs.y));
    hs.z = f2bf(v.z); ls.z = f2bf(v.z - bf2f(hs.z));
    hs.w = f2bf(v.w); ls.w = f2bf(v.w - bf2f(hs.w));
    *(short4*)(Ah + (size_t)row * KPAD + 128 + c0) = hs;
    *(short4*)(Al + (size_t)row * KPAD + 128 + c0) = ls;
}

// Wt layout: [512][384] bf16 (transposed, hi & lo). col g*128+c comes from W_g[:,c].
__global__ __launch_bounds__(384) void k_cvt_W(const float* __restrict__ Wq, const float* __restrict__ Wk,
                                               const float* __restrict__ Wv, const float* __restrict__ Ws,
                                               int koff, int dinW,
                                               short* __restrict__ Wth, short* __restrict__ Wtl)
{
    int col = blockIdx.x;
    int g = col >> 7, c = col & 127;
    const float* W = (g == 0) ? Wq : (g == 1) ? Wk : (g == 2) ? Wv : Ws;
    for (int k = threadIdx.x; k < KPAD; k += blockDim.x) {
        int kr = k - koff;
        float v = (kr >= 0 && kr < dinW) ? W[(size_t)kr * HCX + c] : 0.f;
        short h = f2bf(v);
        Wth[(size_t)col * KPAD + k] = h;
        Wtl[(size_t)col * KPAD + k] = f2bf(v - bf2f(h));
    }
}

// ---------------- MFMA GEMM: qkvs[g] = A @ Wt[g]^T + bias_g  (bf16x3) ----------------
// grid: (Mpad/128, 4), block 256 (4 waves). Block tile 128 rows x 128 cols, BK=32.
__global__ __launch_bounds__(256) void k_gemm(
    const short* __restrict__ Ah, const short* __restrict__ Al,
    const short* __restrict__ Wth, const short* __restrict__ Wtl,
    const float* __restrict__ bq, const float* __restrict__ bk,
    const float* __restrict__ bv, const float* __restrict__ bs,
    float* __restrict__ qkvs, int nN)
{
    __shared__ short AsH[128 * 32];
    __shared__ short AsL[128 * 32];
    __shared__ short BsH[128 * 32];
    __shared__ short BsL[128 * 32];

    const int rowB = blockIdx.x * 128;
    const int g = blockIdx.y;
    const int colB = g * 128;
    const int tid = threadIdx.x;
    const int w = tid >> 6, l = tid & 63;

    f32x4 acc[4][4];
    #pragma unroll
    for (int i = 0; i < 4; ++i)
        #pragma unroll
        for (int j = 0; j < 4; ++j)
            acc[i][j] = (f32x4){0.f, 0.f, 0.f, 0.f};

    const int lrow4 = l >> 2;                       // 0..15
    const int gch = (l & 3) ^ ((l >> 3) & 3);       // inverse-swizzled source chunk
    const int lr = l & 15, kg = l >> 4;

    for (int ks = 0; ks < KPAD / 32; ++ks) {
        const int k0 = ks * 32;
        #pragma unroll
        for (int jj = 0; jj < 2; ++jj) {
            int j = w + jj * 4;                     // 0..7 (16-row groups)
            int rr = j * 16 + lrow4;
            size_t aoff = (size_t)(rowB + rr) * KPAD + k0 + gch * 8;
            size_t boff = (size_t)(colB + rr) * KPAD + k0 + gch * 8;
            gload16(Ah  + aoff, AsH + j * 512);
            gload16(Al  + aoff, AsL + j * 512);
            gload16(Wth + boff, BsH + j * 512);
            gload16(Wtl + boff, BsL + j * 512);
        }
        __syncthreads();

        bf16x8 ah[4], am[4], bh[4], bm[4];
        #pragma unroll
        for (int mi = 0; mi < 4; ++mi) {
            int r = (w >> 1) * 64 + mi * 16 + lr;
            int ch = kg ^ ((r >> 1) & 3);
            int off = r * 32 + ch * 8;
            ah[mi] = *(const bf16x8*)(AsH + off);
            am[mi] = *(const bf16x8*)(AsL + off);
        }
        #pragma unroll
        for (int ni = 0; ni < 4; ++ni) {
            int c = (w & 1) * 64 + ni * 16 + lr;
            int ch = kg ^ ((c >> 1) & 3);
            int off = c * 32 + ch * 8;
            bh[ni] = *(const bf16x8*)(BsH + off);
            bm[ni] = *(const bf16x8*)(BsL + off);
        }
        #pragma unroll
        for (int mi = 0; mi < 4; ++mi)
            #pragma unroll
            for (int ni = 0; ni < 4; ++ni) {
                acc[mi][ni] = __builtin_amdgcn_mfma_f32_16x16x32_bf16(ah[mi], bh[ni], acc[mi][ni], 0, 0, 0);
                acc[mi][ni] = __builtin_amdgcn_mfma_f32_16x16x32_bf16(ah[mi], bm[ni], acc[mi][ni], 0, 0, 0);
                acc[mi][ni] = __builtin_amdgcn_mfma_f32_16x16x32_bf16(am[mi], bh[ni], acc[mi][ni], 0, 0, 0);
            }
        __syncthreads();
    }

    const float* bias = (g == 0) ? bq : (g == 1) ? bk : (g == 2) ? bv : bs;
    float* outp = qkvs + (size_t)g * nN * HCX;
    const int lq = l >> 4;
    #pragma unroll
    for (int mi = 0; mi < 4; ++mi)
        #pragma unroll
        for (int ni = 0; ni < 4; ++ni) {
            int c = (w & 1) * 64 + ni * 16 + lr;
            float bb = bias[c];
            #pragma unroll
            for (int j = 0; j < 4; ++j) {
                int r = rowB + (w >> 1) * 64 + mi * 16 + lq * 4 + j;
                if (r < nN) outp[(size_t)r * HCX + c] = acc[mi][ni][j] + bb;
            }
        }
}

// ---------------- qWe[n,h,d] = sum_c q[n,h,c] * We[d, h*32+c] ----------------
// 16 nodes/block; We staged swizzled in LDS (bank-conflict-free).
__global__ __launch_bounds__(256) void k_qwe(const float* __restrict__ qpl,
                                             const float* __restrict__ We,
                                             float* __restrict__ qWe, int nN)
{
    __shared__ float Wes[64 * 128];
    __shared__ float qs[16][128];
    for (int i = threadIdx.x; i < 64 * 128; i += 256) {
        int d = i >> 7, c = i & 127;
        Wes[d * 128 + ((c + d) & 127)] = We[i];
    }
    int nb = blockIdx.x * 16;
    for (int i = threadIdx.x; i < 16 * 128; i += 256) {
        int r = i >> 7, c = i & 127;
        int row = nb + r;
        qs[r][c] = (row < nN) ? qpl[(size_t)row * HCX + c] : 0.f;
    }
    __syncthreads();
    int h = threadIdx.x >> 6, d = threadIdx.x & 63;
    const int base = h * 32;
    for (int r = 0; r < 16; ++r) {
        int row = nb + r;
        if (row >= nN) break;
        float s = 0.f;
        #pragma unroll
        for (int c = 0; c < 32; ++c)
            s += qs[r][base + c] * Wes[d * 128 + ((base + c + d) & 127)];
        qWe[(size_t)row * 256 + threadIdx.x] = s;
    }
}

// ---------------- fused edge pass: online softmax + aggregation ----------------
// block 256 = 4 waves; wave wv handles node blockIdx*4+wv; lane owns channels l and 64+l
__global__ __launch_bounds__(256) void k_edge(
    const float* __restrict__ qkvs, const float* __restrict__ qWe,
    const float* __restrict__ ea,   const float* __restrict__ We,
    const int* __restrict__ csr_off, const int* __restrict__ edge_sorted,
    const int* __restrict__ src_sorted,
    float* __restrict__ hout, int nN)
{
    __shared__ float wea_s[4][4][64];
    const int wv = threadIdx.x >> 6, l = threadIdx.x & 63;
    const int n = blockIdx.x * 4 + wv;
    const bool active = n < nN;
    int o0 = 0, o1 = 0;
    if (active) { o0 = csr_off[n]; o1 = csr_off[n + 1]; }

    const float* qpl = qkvs;
    const float* kpl = qkvs + (size_t)nN * HCX;
    const float* vpl = qkvs + 2 * (size_t)nN * HCX;

    float qr0 = 0.f, qr1 = 0.f, qw0 = 0.f, qw1 = 0.f, qw2 = 0.f, qw3 = 0.f;
    if (active) {
        qr0 = qpl[(size_t)n * HCX + l];
        qr1 = qpl[(size_t)n * HCX + 64 + l];
        const float* qw = qWe + (size_t)n * 256;
        qw0 = qw[l]; qw1 = qw[64 + l]; qw2 = qw[128 + l]; qw3 = qw[192 + l];
    }
    const int hsel = l >> 5;
    const float scale = 0.17677669529663687f;   // 1/sqrt(32)

    float m0 = -INFINITY, m1 = -INFINITY, m2 = -INFINITY, m3 = -INFINITY;
    float den0 = 0.f, den1 = 0.f, den2 = 0.f, den3 = 0.f;
    float w0 = 0.f, w1 = 0.f, w2 = 0.f, w3 = 0.f;
    float macc0 = 0.f, macc1 = 0.f;

    for (int i = o0; i < o1; ++i) {
        int eid = edge_sorted[i];
        int sn  = src_sorted[i];
        float kv0 = kpl[(size_t)sn * HCX + l];
        float kv1 = kpl[(size_t)sn * HCX + 64 + l];
        float vv0 = vpl[(size_t)sn * HCX + l];
        float vv1 = vpl[(size_t)sn * HCX + 64 + l];
        float eav = ea[(size_t)eid * EDX + l];

        float p1 = qr0 * kv0, p2 = qr1 * kv1;
        #pragma unroll
        for (int s = 1; s < 32; s <<= 1) {
            p1 += __shfl_xor(p1, s);
            p2 += __shfl_xor(p2, s);
        }
        float p1o = __shfl_xor(p1, 32), p2o = __shfl_xor(p2, 32);
        float qk0 = hsel ? p1o : p1, qk1 = hsel ? p1 : p1o;
        float qk2 = hsel ? p2o : p2, qk3 = hsel ? p2 : p2o;

        float t0 = eav * qw0, t1 = eav * qw1, t2 = eav * qw2, t3 = eav * qw3;
        #pragma unroll
        for (int s = 1; s < 64; s <<= 1) {
            t0 += __shfl_xor(t0, s); t1 += __shfl_xor(t1, s);
            t2 += __shfl_xor(t2, s); t3 += __shfl_xor(t3, s);
        }

        float s0 = (qk0 + t0) * scale, s1 = (qk1 + t1) * scale;
        float s2 = (qk2 + t2) * scale, s3 = (qk3 + t3) * scale;

        float nm0 = fmaxf(m0, s0), nm1 = fmaxf(m1, s1);
        float nm2 = fmaxf(m2, s2), nm3 = fmaxf(m3, s3);
        float f0 = __expf(m0 - nm0), f1 = __expf(m1 - nm1);
        float f2 = __expf(m2 - nm2), f3 = __expf(m3 - nm3);
        float e0 = __expf(s0 - nm0), e1 = __expf(s1 - nm1);
        float e2 = __expf(s2 - nm2), e3 = __expf(s3 - nm3);
        m0 = nm0; m1 = nm1; m2 = nm2; m3 = nm3;
        den0 = den0 * f0 + e0; den1 = den1 * f1 + e1;
        den2 = den2 * f2 + e2; den3 = den3 * f3 + e3;
        w0 = w0 * f0 + e0 * eav; w1 = w1 * f1 + e1 * eav;
        w2 = w2 * f2 + e2 * eav; w3 = w3 * f3 + e3 * eav;
        float fA = hsel ? f1 : f0, eA = hsel ? e1 : e0;
        float fB = hsel ? f3 : f2, eB = hsel ? e3 : e2;
        macc0 = macc0 * fA + eA * vv0;
        macc1 = macc1 * fB + eB * vv1;
    }

    wea_s[wv][0][l] = w0; wea_s[wv][1][l] = w1;
    wea_s[wv][2][l] = w2; wea_s[wv][3][l] = w3;
    __syncthreads();

    float acc1 = macc0, acc2 = macc1;
    const int h1 = hsel, h2 = 2 + hsel;
    #pragma unroll 8
    for (int d = 0; d < 64; ++d) {
        acc1 += wea_s[wv][h1][d] * We[d * HCX + l];
        acc2 += wea_s[wv][h2][d] * We[d * HCX + 64 + l];
    }
    if (active) {
        float d1 = (hsel ? den1 : den0) + 1e-16f;
        float d2 = (hsel ? den3 : den2) + 1e-16f;
        const float* spl = qkvs + 3 * (size_t)nN * HCX + (size_t)n * HCX;
        hout[(size_t)n * HCX + l]      = acc1 / d1 + spl[l];
        hout[(size_t)n * HCX + 64 + l] = acc2 / d2 + spl[64 + l];
    }
}

// ---------------- final: out = h @ Wout + bout ----------------
__global__ __launch_bounds__(256) void k_out(const float* __restrict__ h,
                                             const float* __restrict__ Wout,
                                             const float* __restrict__ bout,
                                             float* __restrict__ out, int nN)
{
    __shared__ float hs[8][128];
    int nb = blockIdx.x * 8;
    for (int i = threadIdx.x; i < 8 * 128; i += 256) {
        int r = i >> 7, c = i & 127;
        int row = nb + r;
        hs[r][c] = (row < nN) ? h[(size_t)row * 128 + c] : 0.f;
    }
    __syncthreads();
    int r = threadIdx.x >> 5, col = threadIdx.x & 31;
    int row = nb + r;
    if (row < nN) {
        float s = bout[col];
        #pragma unroll 16
        for (int c = 0; c < 128; ++c) s += hs[r][c] * Wout[c * 32 + col];
        out[(size_t)row * 32 + col] = s;
    }
}

// ---------------- host ----------------
static inline size_t align_up(size_t v, size_t a) { return (v + a - 1) & ~(a - 1); }

extern "C" void kernel_launch(void* const* d_in, const int* in_sizes, int n_in,
                              void* d_out, int out_size, void* d_ws, size_t ws_size,
                              hipStream_t stream)
{
    const float* x  = (const float*)d_in[0];
    const int*   ei = (const int*)d_in[1];
    const float* ea = (const float*)d_in[2];
    const int nN = in_sizes[0] / 256;
    const int nE = in_sizes[1] / 2;
    const int Mpad = (nN + 127) & ~127;
    const int* src = ei;
    const int* dst = ei + nE;

    char* p = (char*)d_ws;
    size_t off = 0;
    auto take = [&](size_t bytes) { void* r = p + off; off = align_up(off + bytes, 256); return r; };
    int* csr_off     = (int*)take((size_t)(nN + 1) * 4);
    int* cursor      = (int*)take((size_t)nN * 4);
    int* deg         = (int*)take((size_t)nN * 4);
    int* edge_sorted = (int*)take((size_t)nE * 4);
    int* src_sorted  = (int*)take((size_t)nE * 4);
    float* qkvs = (float*)take((size_t)4 * nN * HCX * 4);
    float* qWe  = (float*)take((size_t)nN * 256 * 4);
    float* h0   = (float*)take((size_t)nN * HCX * 4);
    float* h1   = (float*)take((size_t)nN * HCX * 4);
    short* Ah   = (short*)take((size_t)Mpad * KPAD * 2);
    short* Al   = (short*)take((size_t)Mpad * KPAD * 2);
    short* Wth  = (short*)take((size_t)512 * KPAD * 2);
    short* Wtl  = (short*)take((size_t)512 * KPAD * 2);
    (void)ws_size; (void)n_in; (void)out_size;

    // CSR by dst (fixed across layers)
    k_zero_deg<<<(nN + 255) / 256, 256, 0, stream>>>(deg, nN);
    k_hist<<<(nE + 255) / 256, 256, 0, stream>>>(dst, deg, nE);
    k_scan<<<1, 1024, 0, stream>>>(deg, csr_off, cursor, nN);
    k_scatter<<<(nE + 255) / 256, 256, 0, stream>>>(dst, src, cursor, edge_sorted, src_sorted, nE);

    // x-part of A (cols 128..383), converted once
    k_cvt_x<<<(Mpad * 64 + 255) / 256, 256, 0, stream>>>(x, Ah, Al, nN, Mpad);

    auto layer = [&](const float* pH, int has_h, int base, float* hout) {
        const float* Wq = (const float*)d_in[base + 0];
        const float* bq = (const float*)d_in[base + 1];
        const float* Wk = (const float*)d_in[base + 2];
        const float* bk = (const float*)d_in[base + 3];
        const float* Wv = (const float*)d_in[base + 4];
        const float* bv = (const float*)d_in[base + 5];
        const float* We = (const float*)d_in[base + 6];
        const float* Ws = (const float*)d_in[base + 7];
        const float* bs = (const float*)d_in[base + 8];
        int koff = has_h ? 0 : 128;
        int dinW = has_h ? 384 : 256;
        k_cvt_h<<<(Mpad * 32 + 255) / 256, 256, 0, stream>>>(pH, has_h, Ah, Al, nN, Mpad);
        k_cvt_W<<<512, 384, 0, stream>>>(Wq, Wk, Wv, Ws, koff, dinW, Wth, Wtl);
        dim3 gg(Mpad / 128, 4);
        k_gemm<<<gg, 256, 0, stream>>>(Ah, Al, Wth, Wtl, bq, bk, bv, bs, qkvs, nN);
        k_qwe<<<(nN + 15) / 16, 256, 0, stream>>>(qkvs, We, qWe, nN);
        k_edge<<<(nN + 3) / 4, 256, 0, stream>>>(qkvs, qWe, ea, We,
                                                 csr_off, edge_sorted, src_sorted, hout, nN);
    };

    layer(nullptr, 0, 3,  h0);   // layer 0: input = x only (h-cols zero)
    layer(h0, 1,   12, h1);      // layer 1: input = [h0 | x]
    layer(h1, 1,   21, h0);      // layer 2: input = [h1 | x]

    k_out<<<(nN + 7) / 8, 256, 0, stream>>>(h0, (const float*)d_in[30], (const float*)d_in[31],
                                            (float*)d_out, nN);
}